// Round 1
// baseline (490.539 us; speedup 1.0000x reference)
//
#include <hip/hip_runtime.h>

// CumSumLoop: x [B=128, T=8192, C=64] fp32, running cumsum over T, + s_init[C].
// Two-pass chunked scan. Partials stashed in d_out (no ws needed).

#define B   128
#define T   8192
#define C   64
#define NC  64          // chunks along T
#define L   (T / NC)    // 128 t-steps per chunk

// ---- Kernel 1: per-chunk channel sums -> out[(b*T + k*L)*C + c] ----
// One wave per (b, k). Lane = channel. Coalesced: 64 consecutive floats per t.
__global__ __launch_bounds__(256) void k_partial(const float* __restrict__ x,
                                                 float* __restrict__ out) {
    const int w = blockIdx.x * 4 + (threadIdx.x >> 6);   // wave id = b*NC + k
    const int c = threadIdx.x & 63;
    const int b = w >> 6;          // / NC
    const int k = w & (NC - 1);    // % NC
    const size_t base = ((size_t)b * T + (size_t)k * L) * C + c;
    float s = 0.f;
    #pragma unroll 8
    for (int t = 0; t < L; ++t)
        s += x[base + (size_t)t * C];
    out[base] = s;
}

// ---- Kernel 2: exclusive scan of partials along k, seeded with s_init ----
// Thread = (b, c); 8192 threads. In-place in the stash slots of d_out.
__global__ __launch_bounds__(256) void k_scan(const float* __restrict__ s_init,
                                              float* __restrict__ out) {
    const int tid = blockIdx.x * blockDim.x + threadIdx.x; // b*C + c
    const int b = tid >> 6;
    const int c = tid & 63;
    const size_t base = (size_t)b * T * C + c;
    float off = s_init[c];
    #pragma unroll 8
    for (int k = 0; k < NC; ++k) {
        const size_t idx = base + (size_t)k * L * C;
        const float p = out[idx];
        out[idx] = off;
        off += p;
    }
}

// ---- Kernel 3: local inclusive scan + offset, nontemporal y stores ----
__global__ __launch_bounds__(256) void k_write(const float* __restrict__ x,
                                               float* __restrict__ out) {
    const int w = blockIdx.x * 4 + (threadIdx.x >> 6);
    const int c = threadIdx.x & 63;
    const int b = w >> 6;
    const int k = w & (NC - 1);
    const size_t base = ((size_t)b * T + (size_t)k * L) * C + c;
    float run = out[base];   // exclusive offset (includes s_init)
    #pragma unroll 4
    for (int t = 0; t < L; ++t) {
        run += x[base + (size_t)t * C];
        __builtin_nontemporal_store(run, &out[base + (size_t)t * C]);
    }
}

extern "C" void kernel_launch(void* const* d_in, const int* in_sizes, int n_in,
                              void* d_out, int out_size, void* d_ws, size_t ws_size,
                              hipStream_t stream) {
    const float* x      = (const float*)d_in[0];
    const float* s_init = (const float*)d_in[1];
    float* out          = (float*)d_out;

    const int waves = B * NC;                 // 8192
    dim3 blk(256);
    dim3 grd1(waves / 4);                     // 2048 blocks, 4 waves each
    dim3 grd2((B * C) / 256);                 // 32 blocks

    k_partial<<<grd1, blk, 0, stream>>>(x, out);
    k_scan   <<<grd2, blk, 0, stream>>>(s_init, out);
    k_write  <<<grd1, blk, 0, stream>>>(x, out);
}

// Round 2
// 479.520 us; speedup vs baseline: 1.0230x; 1.0230x over previous
//
#include <hip/hip_runtime.h>

// CumSumLoop: x [B=128, T=8192, C=64] fp32, running cumsum over T, + s_init[C].
// Two-pass chunked scan, float4-vectorized (4 channels/thread, 16 threads/chunk).
// Partials stashed in d_out at each chunk's t=0 row (overwritten by K3).

typedef float f4 __attribute__((ext_vector_type(4)));

#define B    128
#define T    8192
#define C    64
#define NC   64           // chunks along T
#define L    (T / NC)     // 128 t-steps per chunk
#define ROW4 (C / 4)      // 16 float4 per t-row
#define CH4  (L * ROW4)   // 512 float4 per chunk

// ---- K1: per-chunk channel sums. Thread = (chunk, g); g = float4 channel group.
__global__ __launch_bounds__(256) void k_partial(const f4* __restrict__ x,
                                                 f4* __restrict__ out) {
    const int tid   = blockIdx.x * 256 + threadIdx.x;
    const int chunk = tid >> 4;          // b*NC + k  (chunks are contiguous in memory)
    const int g     = tid & 15;
    const size_t base = (size_t)chunk * CH4 + g;
    f4 s = {0.f, 0.f, 0.f, 0.f};
    #pragma unroll 8
    for (int t = 0; t < L; ++t)
        s += x[base + (size_t)t * ROW4];
    out[base] = s;
}

// ---- K2: exclusive scan of partials along k, seeded with s_init. Thread = (b, g).
__global__ __launch_bounds__(256) void k_scan(const f4* __restrict__ s_init,
                                              f4* __restrict__ out) {
    const int tid = blockIdx.x * 256 + threadIdx.x;   // b*16 + g, 2048 total
    const int b   = tid >> 4;
    const int g   = tid & 15;
    f4 off = s_init[g];
    size_t idx = (size_t)b * NC * CH4 + g;
    #pragma unroll 4
    for (int k = 0; k < NC; ++k, idx += CH4) {
        const f4 p = out[idx];
        out[idx] = off;
        off += p;
    }
}

// ---- K3: local inclusive scan + offset; nontemporal y stores (keep x in L3).
__global__ __launch_bounds__(256) void k_write(const f4* __restrict__ x,
                                               f4* __restrict__ out) {
    const int tid   = blockIdx.x * 256 + threadIdx.x;
    const int chunk = tid >> 4;
    const int g     = tid & 15;
    const size_t base = (size_t)chunk * CH4 + g;
    f4 run = out[base];                  // exclusive offset (includes s_init)
    #pragma unroll 8
    for (int t = 0; t < L; ++t) {
        run += x[base + (size_t)t * ROW4];
        __builtin_nontemporal_store(run, &out[base + (size_t)t * ROW4]);
    }
}

extern "C" void kernel_launch(void* const* d_in, const int* in_sizes, int n_in,
                              void* d_out, int out_size, void* d_ws, size_t ws_size,
                              hipStream_t stream) {
    const f4* x      = (const f4*)d_in[0];
    const f4* s_init = (const f4*)d_in[1];
    f4* out          = (f4*)d_out;

    dim3 blk(256);
    dim3 grd1((B * NC * 16) / 256);      // 512 blocks, 4 chunks/wave
    dim3 grd2((B * 16) / 256);           // 8 blocks

    k_partial<<<grd1, blk, 0, stream>>>(x, out);
    k_scan   <<<grd2, blk, 0, stream>>>(s_init, out);
    k_write  <<<grd1, blk, 0, stream>>>(x, out);
}